// Round 2
// baseline (304.946 us; speedup 1.0000x reference)
//
#include <hip/hip_runtime.h>

typedef unsigned short u16;
typedef unsigned int u32;
typedef __attribute__((ext_vector_type(8))) short bf16x8;
typedef __attribute__((ext_vector_type(4))) float f32x4;

__device__ __forceinline__ u16 f2bf(float f) {
    u32 u = __builtin_bit_cast(u32, f);
    u += 0x7FFFu + ((u >> 16) & 1u);
    return (u16)(u >> 16);
}
__device__ __forceinline__ float bf2f(u16 s) {
    u32 u = ((u32)s) << 16;
    return __builtin_bit_cast(float, u);
}
__device__ __forceinline__ float sigm(float x) {
    return 1.0f / (1.0f + __expf(-x));
}
__device__ __forceinline__ void gload16(const u16* g, u16* l) {
    __builtin_amdgcn_global_load_lds(
        (const __attribute__((address_space(1))) void*)g,
        (__attribute__((address_space(3))) void*)l, 16, 0, 0);
}

// ---------------- P1: x (B,C,H,W) fp32 -> x' [p][c] bf16, p=(b*64+h)*64+w ----
__global__ __launch_bounds__(256) void transpose_in(const float* __restrict__ x,
                                                    u16* __restrict__ xp) {
    __shared__ float tile[64][65];
    int bid = blockIdx.x;
    int ct = bid & 3, h = (bid >> 2) & 63, b = bid >> 8;
    int t = threadIdx.x;
    int tr = t >> 4, tc = t & 15;
    const float* src = x + (((size_t)(b * 256 + ct * 64) * 64 + h) * 64);
#pragma unroll
    for (int i = 0; i < 4; ++i) {
        int c = tr + i * 16;
        float4 v = *(const float4*)(src + (size_t)c * 4096 + tc * 4);
        tile[c][tc * 4 + 0] = v.x;
        tile[c][tc * 4 + 1] = v.y;
        tile[c][tc * 4 + 2] = v.z;
        tile[c][tc * 4 + 3] = v.w;
    }
    __syncthreads();
    u16* dst = xp + ((size_t)((b * 64 + h) * 64)) * 256 + ct * 64;
#pragma unroll
    for (int i = 0; i < 4; ++i) {
        int w = tr + i * 16;
        ushort4 o;
        o.x = f2bf(tile[tc * 4 + 0][w]);
        o.y = f2bf(tile[tc * 4 + 1][w]);
        o.z = f2bf(tile[tc * 4 + 2][w]);
        o.w = f2bf(tile[tc * 4 + 3][w]);
        *(ushort4*)(dst + (size_t)w * 256 + tc * 4) = o;
    }
}

// ---------------- weight prep ------------------------------------------------
__global__ __launch_bounds__(256) void prep_w(const float* __restrict__ qw,
                                              const float* __restrict__ qb,
                                              const float* __restrict__ fw,
                                              const float* __restrict__ fb,
                                              float* __restrict__ wq0,
                                              u16* __restrict__ wkv,
                                              float* __restrict__ bkv,
                                              u16* __restrict__ wf,
                                              float* __restrict__ bff) {
    int i = blockIdx.x * 256 + threadIdx.x;
    if (i < 513 * 256) {
        int o = i >> 8, c = i & 255;
        float v = qw[i];
        if (o == 0) wq0[c] = v;
        else        wkv[(size_t)(o - 1) * 256 + c] = f2bf(v);
    }
    if (i < 65536) wf[i] = f2bf(fw[i]);
    if (i < 512)   bkv[i] = qb[i + 1];
    if (i < 256)   bff[i] = fb[i];
}

// ---------------- qdot: q[p] = x'[p,:] . wq0 ---------------------------------
__global__ __launch_bounds__(256) void qdot(const u16* __restrict__ A,
                                            const float* __restrict__ wq0,
                                            float* __restrict__ q) {
    int t = threadIdx.x;
    int row = blockIdx.x * 64 + (t >> 2);
    int c0 = (t & 3) * 64;
    const u16* ar = A + (size_t)row * 256 + c0;
    float a = 0.f;
#pragma unroll
    for (int i = 0; i < 8; ++i) {
        bf16x8 v = *(const bf16x8*)(ar + i * 8);
#pragma unroll
        for (int j = 0; j < 8; ++j) a += bf2f((u16)v[j]) * wq0[c0 + i * 8 + j];
    }
    a += __shfl_xor(a, 1);
    a += __shfl_xor(a, 2);
    if ((t & 3) == 0) q[row] = a;
}

// ---------------- ctx_gate: softmax + context + gated residual ---------------
// G may alias key (rows staged to LDS before overwrite; rows disjoint per block)
__global__ __launch_bounds__(256) void ctx_gate(const float* __restrict__ qbuf,
                                                const u16* __restrict__ key,
                                                const u16* __restrict__ x,
                                                const u16* __restrict__ v,
                                                u16* __restrict__ G, int axis) {
    __shared__ alignas(16) u16 kl[64 * 256];
    __shared__ float sc[64];
    __shared__ float ctx[256];
    int l = blockIdx.x, t = threadIdx.x;
    int b = l >> 6, lw = l & 63;
    auto pj = [&](int j) {
        return axis ? (b * 4096 + j * 64 + lw) : (l * 64 + j);
    };
    if (t < 64) {
        float qv = qbuf[pj(t)];
        float m = qv;
#pragma unroll
        for (int off = 32; off > 0; off >>= 1) m = fmaxf(m, __shfl_xor(m, off));
        float e = __expf(qv - m);
        float s = e;
#pragma unroll
        for (int off = 32; off > 0; off >>= 1) s += __shfl_xor(s, off);
        sc[t] = e / s;
    }
    int j = t >> 2, c0 = (t & 3) * 64;
    {
        const u16* kr = key + (size_t)pj(j) * 256 + c0;
#pragma unroll
        for (int i = 0; i < 8; ++i)
            *(bf16x8*)&kl[j * 256 + c0 + i * 8] = *(const bf16x8*)(kr + i * 8);
    }
    __syncthreads();
    {
        float a = 0.f;
#pragma unroll 8
        for (int jj = 0; jj < 64; ++jj) a += bf2f(kl[jj * 256 + t]) * sc[jj];
        ctx[t] = a;
    }
    __syncthreads();
    {
        int p = pj(j);
        const u16* xr = x + (size_t)p * 256 + c0;
        const u16* vr = v + (size_t)p * 256 + c0;
        u16* gr = G + (size_t)p * 256 + c0;
#pragma unroll
        for (int i = 0; i < 8; ++i) {
            bf16x8 xv = *(const bf16x8*)(xr + i * 8);
            bf16x8 vv = *(const bf16x8*)(vr + i * 8);
            u16 o[8];
#pragma unroll
            for (int j2 = 0; j2 < 8; ++j2)
                o[j2] = f2bf(bf2f((u16)xv[j2]) +
                             sigm(bf2f((u16)vv[j2])) * ctx[c0 + i * 8 + j2]);
            *(bf16x8*)(gr + i * 8) = *(bf16x8*)o;
        }
    }
}

// ---------------- GEMM (pure): MODE 0 = qkv (key/val), 1 = fus->bf16, 2 = fus->fp32 transposed
template <int MODE>
__global__ __launch_bounds__(256, 2) void gemm_k(
    const u16* __restrict__ A, const u16* __restrict__ Bw,
    const float* __restrict__ bias,
    u16* __restrict__ keyOut, u16* __restrict__ valOut,
    float* __restrict__ fOut) {
    __shared__ alignas(16) u16 Asm[128 * 64];
    __shared__ alignas(16) u16 Bsm[128 * 64];
    int bid = blockIdx.x;
    int otile, ptile;
    if (MODE == 0) { otile = bid & 3; ptile = bid >> 2; }
    else           { otile = bid & 1; ptile = bid >> 1; }
    int p0 = ptile * 128, o0 = otile * 128;
    int t = threadIdx.x, lane = t & 63, wv = t >> 6;
    int wm = (wv >> 1) * 64, wn = (wv & 1) * 64;
    int l7 = lane & 7;
    // staging: lane covers row (lane>>3), linear LDS chunk (lane&7);
    // source chunk = (lane&7) ^ (row&7)  (involution -> swizzled storage)
    int srcoff = (lane >> 3) * 256 + (((lane & 7) ^ (lane >> 3)) * 8);
    int arow = lane & 15, kgrp = lane >> 4;
    f32x4 zero = {0.f, 0.f, 0.f, 0.f};
    f32x4 acc[4][4];
#pragma unroll
    for (int i = 0; i < 4; ++i)
#pragma unroll
        for (int jj = 0; jj < 4; ++jj) acc[i][jj] = zero;

    for (int k0 = 0; k0 < 256; k0 += 64) {
        __syncthreads();
#pragma unroll
        for (int it = 0; it < 4; ++it) {
            int r0 = it * 32 + wv * 8;
            gload16(A + (size_t)(p0 + r0) * 256 + k0 + srcoff, &Asm[r0 * 64]);
            gload16(Bw + (size_t)(o0 + r0) * 256 + k0 + srcoff, &Bsm[r0 * 64]);
        }
        __syncthreads();
#pragma unroll
        for (int kk = 0; kk < 64; kk += 32) {
            int soff = (((kk >> 3) + kgrp) ^ l7) << 3;
            bf16x8 af[4], bfv[4];
#pragma unroll
            for (int mi = 0; mi < 4; ++mi)
                af[mi] = *(const bf16x8*)&Asm[(wm + mi * 16 + arow) * 64 + soff];
#pragma unroll
            for (int ni = 0; ni < 4; ++ni)
                bfv[ni] = *(const bf16x8*)&Bsm[(wn + ni * 16 + arow) * 64 + soff];
#pragma unroll
            for (int mi = 0; mi < 4; ++mi)
#pragma unroll
                for (int ni = 0; ni < 4; ++ni)
                    acc[mi][ni] = __builtin_amdgcn_mfma_f32_16x16x32_bf16(
                        af[mi], bfv[ni], acc[mi][ni], 0, 0, 0);
        }
    }
#pragma unroll
    for (int mi = 0; mi < 4; ++mi) {
#pragma unroll
        for (int ni = 0; ni < 4; ++ni) {
            int col = o0 + wn + ni * 16 + arow;
            float bv = bias[col];
#pragma unroll
            for (int r = 0; r < 4; ++r) {
                int row = p0 + wm + mi * 16 + ((lane >> 4) << 2) + r;
                float v = acc[mi][ni][r] + bv;
                if (MODE == 0) {
                    if (col < 256) keyOut[(size_t)row * 256 + col] = f2bf(v);
                    else           valOut[(size_t)row * 256 + (col - 256)] = f2bf(v);
                } else if (MODE == 1) {
                    keyOut[(size_t)row * 256 + col] = f2bf(v);
                } else {
                    fOut[((size_t)((row >> 12) * 256 + col)) * 4096 + (row & 4095)] = v;
                }
            }
        }
    }
}

// ---------------- host ----------------
extern "C" void kernel_launch(void* const* d_in, const int* in_sizes, int n_in,
                              void* d_out, int out_size, void* d_ws, size_t ws_size,
                              hipStream_t stream) {
    const float* x   = (const float*)d_in[0];
    const float* qWw = (const float*)d_in[1];
    const float* qWb = (const float*)d_in[2];
    const float* qHw = (const float*)d_in[3];
    const float* qHb = (const float*)d_in[4];
    const float* fWw = (const float*)d_in[5];
    const float* fWb = (const float*)d_in[6];
    const float* fHw = (const float*)d_in[7];
    const float* fHb = (const float*)d_in[8];
    float* out = (float*)d_out;

    char* ws = (char*)d_ws;
    size_t off = 0;
    auto carve = [&](size_t bytes) -> void* {
        off = (off + 255) & ~(size_t)255;
        void* p = ws + off;
        off += bytes;
        return p;
    };
    const size_t P = 65536;
    u16*   xp  = (u16*)carve(P * 256 * 2);   // x' (stage1) / val2 (stage2)
    u16*   kb  = (u16*)carve(P * 256 * 2);   // key / G (in-place)
    u16*   vb  = (u16*)carve(P * 256 * 2);   // val1 / x_w'
    float* q   = (float*)carve(P * 4);
    float* wq01 = (float*)carve(256 * 4);
    u16*   wkv1 = (u16*)carve(512 * 256 * 2);
    float* bkv1 = (float*)carve(512 * 4);
    u16*   wf1  = (u16*)carve(65536 * 2);
    float* bf1  = (float*)carve(256 * 4);
    float* wq02 = (float*)carve(256 * 4);
    u16*   wkv2 = (u16*)carve(512 * 256 * 2);
    float* bkv2 = (float*)carve(512 * 4);
    u16*   wf2  = (u16*)carve(65536 * 2);
    float* bf2  = (float*)carve(256 * 4);

    prep_w<<<513, 256, 0, stream>>>(qWw, qWb, fWw, fWb, wq01, wkv1, bkv1, wf1, bf1);
    prep_w<<<513, 256, 0, stream>>>(qHw, qHb, fHw, fHb, wq02, wkv2, bkv2, wf2, bf2);
    transpose_in<<<4096, 256, 0, stream>>>(x, xp);

    // ---- stage 1 (axis = W) ----
    gemm_k<0><<<2048, 256, 0, stream>>>(xp, wkv1, bkv1, kb, vb, nullptr);
    qdot<<<1024, 256, 0, stream>>>(xp, wq01, q);
    ctx_gate<<<1024, 256, 0, stream>>>(q, kb, xp, vb, kb, 0);        // G -> kb
    gemm_k<1><<<1024, 256, 0, stream>>>(kb, wf1, bf1, vb, nullptr, nullptr);  // x_w' -> vb
    // ---- stage 2 (axis = H) ----
    gemm_k<0><<<2048, 256, 0, stream>>>(vb, wkv2, bkv2, kb, xp, nullptr);     // key2->kb, val2->xp
    qdot<<<1024, 256, 0, stream>>>(vb, wq02, q);
    ctx_gate<<<1024, 256, 0, stream>>>(q, kb, vb, xp, kb, 1);        // G -> kb
    gemm_k<2><<<1024, 256, 0, stream>>>(kb, wf2, bf2, nullptr, nullptr, out);
    (void)in_sizes; (void)n_in; (void)out_size; (void)ws_size;
}

// Round 3
// 176.814 us; speedup vs baseline: 1.7247x; 1.7247x over previous
//
#include <hip/hip_runtime.h>

typedef unsigned short u16;
typedef unsigned int u32;
typedef __attribute__((ext_vector_type(8))) short bf16x8;
typedef __attribute__((ext_vector_type(4))) float f32x4;

__device__ __forceinline__ u16 f2bf(float f) {
    u32 u = __builtin_bit_cast(u32, f);
    u += 0x7FFFu + ((u >> 16) & 1u);
    return (u16)(u >> 16);
}
__device__ __forceinline__ float bf2f(u16 s) {
    u32 u = ((u32)s) << 16;
    return __builtin_bit_cast(float, u);
}
__device__ __forceinline__ float sigm(float x) {
    return 1.0f / (1.0f + __expf(-x));
}
__device__ __forceinline__ void gload16(const u16* g, u16* l) {
    __builtin_amdgcn_global_load_lds(
        (const __attribute__((address_space(1))) void*)g,
        (__attribute__((address_space(3))) void*)l, 16, 0, 0);
}

// ---------------- P1: x (B,C,H,W) fp32 -> x' [p][c] bf16, p=(b*64+h)*64+w ----
__global__ __launch_bounds__(256) void transpose_in(const float* __restrict__ x,
                                                    u16* __restrict__ xp) {
    __shared__ float tile[64][65];
    int bid = blockIdx.x;
    int ct = bid & 3, h = (bid >> 2) & 63, b = bid >> 8;
    int t = threadIdx.x;
    int tr = t >> 4, tc = t & 15;
    const float* src = x + (((size_t)(b * 256 + ct * 64) * 64 + h) * 64);
#pragma unroll
    for (int i = 0; i < 4; ++i) {
        int c = tr + i * 16;
        float4 v = *(const float4*)(src + (size_t)c * 4096 + tc * 4);
        tile[c][tc * 4 + 0] = v.x;
        tile[c][tc * 4 + 1] = v.y;
        tile[c][tc * 4 + 2] = v.z;
        tile[c][tc * 4 + 3] = v.w;
    }
    __syncthreads();
    u16* dst = xp + ((size_t)((b * 64 + h) * 64)) * 256 + ct * 64;
#pragma unroll
    for (int i = 0; i < 4; ++i) {
        int w = tr + i * 16;
        ushort4 o;
        o.x = f2bf(tile[tc * 4 + 0][w]);
        o.y = f2bf(tile[tc * 4 + 1][w]);
        o.z = f2bf(tile[tc * 4 + 2][w]);
        o.w = f2bf(tile[tc * 4 + 3][w]);
        *(ushort4*)(dst + (size_t)w * 256 + tc * 4) = o;
    }
}

// ---------------- weight prep ------------------------------------------------
__global__ __launch_bounds__(256) void prep_w(const float* __restrict__ qw,
                                              const float* __restrict__ qb,
                                              const float* __restrict__ fw,
                                              const float* __restrict__ fb,
                                              float* __restrict__ wq0,
                                              u16* __restrict__ wkv,
                                              float* __restrict__ bkv,
                                              u16* __restrict__ wf,
                                              float* __restrict__ bff) {
    int i = blockIdx.x * 256 + threadIdx.x;
    if (i < 513 * 256) {
        int o = i >> 8, c = i & 255;
        float v = qw[i];
        if (o == 0) wq0[c] = v;
        else        wkv[(size_t)(o - 1) * 256 + c] = f2bf(v);
    }
    if (i < 65536) wf[i] = f2bf(fw[i]);
    if (i < 512)   bkv[i] = qb[i + 1];
    if (i < 256)   bff[i] = fb[i];
}

// ---------------- ctx_gate v3: q-dot + softmax + context + gated residual ----
// No bulk LDS staging. G may alias key (key fully read in phase B before
// phase C writes; blocks own disjoint line-row-sets).
__global__ __launch_bounds__(256) void ctx_gate(const u16* __restrict__ Xin,
                                                const float* __restrict__ wq0,
                                                const u16* __restrict__ key,
                                                const u16* __restrict__ val,
                                                u16* __restrict__ G, int axis) {
    __shared__ float ql[64];
    __shared__ float sc[64];
    __shared__ alignas(16) float ctxs[256];
    int l = blockIdx.x, t = threadIdx.x;
    int b = l >> 6, lw = l & 63;
    auto pj = [&](int j) {
        return axis ? (b * 4096 + j * 64 + lw) : (l * 64 + j);
    };
    // ---- phase A: q_j = X[p_j,:] . wq0 (quad per row) ----
    {
        int j = t >> 2, g = t & 3;
        const u16* xr = Xin + (size_t)pj(j) * 256 + g * 64;
        const float* wp = wq0 + g * 64;
        float a0 = 0.f, a1 = 0.f;
#pragma unroll
        for (int i = 0; i < 8; ++i) {
            bf16x8 v = *(const bf16x8*)(xr + i * 8);
#pragma unroll
            for (int jj = 0; jj < 8; ++jj) {
                float p = bf2f((u16)v[jj]) * wp[i * 8 + jj];
                if (jj & 1) a1 += p; else a0 += p;
            }
        }
        float a = a0 + a1;
        a += __shfl_xor(a, 1);
        a += __shfl_xor(a, 2);
        if (g == 0) ql[j] = a;
    }
    __syncthreads();
    // ---- softmax over the 64 line elements ----
    if (t < 64) {
        float qv = ql[t];
        float m = qv;
#pragma unroll
        for (int off = 32; off > 0; off >>= 1) m = fmaxf(m, __shfl_xor(m, off));
        float e = __expf(qv - m);
        float s = e;
#pragma unroll
        for (int off = 32; off > 0; off >>= 1) s += __shfl_xor(s, off);
        sc[t] = e / s;
    }
    __syncthreads();
    // ---- phase B: ctx[c] = sum_j sc[j]*key[p_j][c], thread owns channel t ----
    {
        float a0 = 0.f, a1 = 0.f;
#pragma unroll 4
        for (int j2 = 0; j2 < 64; j2 += 2) {
            a0 += bf2f(key[(size_t)pj(j2) * 256 + t]) * sc[j2];
            a1 += bf2f(key[(size_t)pj(j2 + 1) * 256 + t]) * sc[j2 + 1];
        }
        ctxs[t] = a0 + a1;
    }
    __syncthreads();
    // ---- phase C: G = X + sigmoid(V)*ctx, wave-contiguous rows ----
    {
        int c0 = (t & 31) * 8;
        float cf[8];
        *(float4*)cf = *(const float4*)&ctxs[c0];
        *(float4*)(cf + 4) = *(const float4*)&ctxs[c0 + 4];
#pragma unroll
        for (int it = 0; it < 8; ++it) {
            int j3 = it * 8 + (t >> 5);
            size_t base = (size_t)pj(j3) * 256 + c0;
            bf16x8 xv = *(const bf16x8*)(Xin + base);
            bf16x8 vv = *(const bf16x8*)(val + base);
            u16 o[8];
#pragma unroll
            for (int jj = 0; jj < 8; ++jj)
                o[jj] = f2bf(bf2f((u16)xv[jj]) +
                             sigm(bf2f((u16)vv[jj])) * cf[jj]);
            *(bf16x8*)(G + base) = *(bf16x8*)o;
        }
    }
}

// ---------------- GEMM (pure): MODE 0 = qkv (key/val), 1 = fus->bf16, 2 = fus->fp32 transposed
// XCD-chunked block swizzle: xcd owns contiguous p-tile range, o-tiles adjacent.
template <int MODE>
__global__ __launch_bounds__(256, 2) void gemm_k(
    const u16* __restrict__ A, const u16* __restrict__ Bw,
    const float* __restrict__ bias,
    u16* __restrict__ keyOut, u16* __restrict__ valOut,
    float* __restrict__ fOut) {
    int h = blockIdx.x;
    int xcd = h & 7, slot = h >> 3;
    int otile, ptile;
    if (MODE == 0) { otile = slot & 3; ptile = xcd * 64 + (slot >> 2); }
    else           { otile = slot & 1; ptile = xcd * 64 + (slot >> 1); }
    __shared__ alignas(16) u16 Asm[128 * 64];
    __shared__ alignas(16) u16 Bsm[128 * 64];
    int p0 = ptile * 128, o0 = otile * 128;
    int t = threadIdx.x, lane = t & 63, wv = t >> 6;
    int wm = (wv >> 1) * 64, wn = (wv & 1) * 64;
    int l7 = lane & 7;
    int srcoff = (lane >> 3) * 256 + (((lane & 7) ^ (lane >> 3)) * 8);
    int arow = lane & 15, kgrp = lane >> 4;
    f32x4 zero = {0.f, 0.f, 0.f, 0.f};
    f32x4 acc[4][4];
#pragma unroll
    for (int i = 0; i < 4; ++i)
#pragma unroll
        for (int jj = 0; jj < 4; ++jj) acc[i][jj] = zero;

    for (int k0 = 0; k0 < 256; k0 += 64) {
        __syncthreads();
#pragma unroll
        for (int it = 0; it < 4; ++it) {
            int r0 = it * 32 + wv * 8;
            gload16(A + (size_t)(p0 + r0) * 256 + k0 + srcoff, &Asm[r0 * 64]);
            gload16(Bw + (size_t)(o0 + r0) * 256 + k0 + srcoff, &Bsm[r0 * 64]);
        }
        __syncthreads();
#pragma unroll
        for (int kk = 0; kk < 64; kk += 32) {
            int soff = (((kk >> 3) + kgrp) ^ l7) << 3;
            bf16x8 af[4], bfv[4];
#pragma unroll
            for (int mi = 0; mi < 4; ++mi)
                af[mi] = *(const bf16x8*)&Asm[(wm + mi * 16 + arow) * 64 + soff];
#pragma unroll
            for (int ni = 0; ni < 4; ++ni)
                bfv[ni] = *(const bf16x8*)&Bsm[(wn + ni * 16 + arow) * 64 + soff];
#pragma unroll
            for (int mi = 0; mi < 4; ++mi)
#pragma unroll
                for (int ni = 0; ni < 4; ++ni)
                    acc[mi][ni] = __builtin_amdgcn_mfma_f32_16x16x32_bf16(
                        af[mi], bfv[ni], acc[mi][ni], 0, 0, 0);
        }
    }
#pragma unroll
    for (int mi = 0; mi < 4; ++mi) {
#pragma unroll
        for (int ni = 0; ni < 4; ++ni) {
            int col = o0 + wn + ni * 16 + arow;
            float bv = bias[col];
#pragma unroll
            for (int r = 0; r < 4; ++r) {
                int row = p0 + wm + mi * 16 + ((lane >> 4) << 2) + r;
                float v = acc[mi][ni][r] + bv;
                if (MODE == 0) {
                    if (col < 256) keyOut[(size_t)row * 256 + col] = f2bf(v);
                    else           valOut[(size_t)row * 256 + (col - 256)] = f2bf(v);
                } else if (MODE == 1) {
                    keyOut[(size_t)row * 256 + col] = f2bf(v);
                } else {
                    fOut[((size_t)((row >> 12) * 256 + col)) * 4096 + (row & 4095)] = v;
                }
            }
        }
    }
}

// ---------------- host ----------------
extern "C" void kernel_launch(void* const* d_in, const int* in_sizes, int n_in,
                              void* d_out, int out_size, void* d_ws, size_t ws_size,
                              hipStream_t stream) {
    const float* x   = (const float*)d_in[0];
    const float* qWw = (const float*)d_in[1];
    const float* qWb = (const float*)d_in[2];
    const float* qHw = (const float*)d_in[3];
    const float* qHb = (const float*)d_in[4];
    const float* fWw = (const float*)d_in[5];
    const float* fWb = (const float*)d_in[6];
    const float* fHw = (const float*)d_in[7];
    const float* fHb = (const float*)d_in[8];
    float* out = (float*)d_out;

    char* ws = (char*)d_ws;
    size_t off = 0;
    auto carve = [&](size_t bytes) -> void* {
        off = (off + 255) & ~(size_t)255;
        void* p = ws + off;
        off += bytes;
        return p;
    };
    const size_t P = 65536;
    u16*   xp  = (u16*)carve(P * 256 * 2);   // x' (stage1) / val2 (stage2)
    u16*   kb  = (u16*)carve(P * 256 * 2);   // key / G (in-place)
    u16*   vb  = (u16*)carve(P * 256 * 2);   // val1 / x_w'
    float* wq01 = (float*)carve(256 * 4);
    u16*   wkv1 = (u16*)carve(512 * 256 * 2);
    float* bkv1 = (float*)carve(512 * 4);
    u16*   wf1  = (u16*)carve(65536 * 2);
    float* bf1  = (float*)carve(256 * 4);
    float* wq02 = (float*)carve(256 * 4);
    u16*   wkv2 = (u16*)carve(512 * 256 * 2);
    float* bkv2 = (float*)carve(512 * 4);
    u16*   wf2  = (u16*)carve(65536 * 2);
    float* bf2  = (float*)carve(256 * 4);

    prep_w<<<513, 256, 0, stream>>>(qWw, qWb, fWw, fWb, wq01, wkv1, bkv1, wf1, bf1);
    prep_w<<<513, 256, 0, stream>>>(qHw, qHb, fHw, fHb, wq02, wkv2, bkv2, wf2, bf2);
    transpose_in<<<4096, 256, 0, stream>>>(x, xp);

    // ---- stage 1 (axis = W) ----
    gemm_k<0><<<2048, 256, 0, stream>>>(xp, wkv1, bkv1, kb, vb, nullptr);
    ctx_gate<<<1024, 256, 0, stream>>>(xp, wq01, kb, vb, kb, 0);     // G -> kb
    gemm_k<1><<<1024, 256, 0, stream>>>(kb, wf1, bf1, vb, nullptr, nullptr);  // x_w' -> vb
    // ---- stage 2 (axis = H) ----
    gemm_k<0><<<2048, 256, 0, stream>>>(vb, wkv2, bkv2, kb, xp, nullptr);     // key2->kb, val2->xp
    ctx_gate<<<1024, 256, 0, stream>>>(vb, wq02, kb, xp, kb, 1);     // G -> kb
    gemm_k<2><<<1024, 256, 0, stream>>>(kb, wf2, bf2, nullptr, nullptr, out);
    (void)in_sizes; (void)n_in; (void)out_size; (void)ws_size;
}

// Round 4
// 160.592 us; speedup vs baseline: 1.8989x; 1.1010x over previous
//
#include <hip/hip_runtime.h>

typedef unsigned short u16;
typedef unsigned int u32;
typedef __attribute__((ext_vector_type(8))) short bf16x8;
typedef __attribute__((ext_vector_type(4))) float f32x4;

__device__ __forceinline__ u16 f2bf(float f) {
    u32 u = __builtin_bit_cast(u32, f);
    u += 0x7FFFu + ((u >> 16) & 1u);
    return (u16)(u >> 16);
}
__device__ __forceinline__ float bf2f(u16 s) {
    u32 u = ((u32)s) << 16;
    return __builtin_bit_cast(float, u);
}
__device__ __forceinline__ float sigm(float x) {
    return 1.0f / (1.0f + __expf(-x));
}
__device__ __forceinline__ void gload16(const u16* g, u16* l) {
    __builtin_amdgcn_global_load_lds(
        (const __attribute__((address_space(1))) void*)g,
        (__attribute__((address_space(3))) void*)l, 16, 0, 0);
}

// ---------------- P1: x (B,C,H,W) fp32 -> x' [p][c] bf16, p=(b*64+h)*64+w ----
__global__ __launch_bounds__(256) void transpose_in(const float* __restrict__ x,
                                                    u16* __restrict__ xp) {
    __shared__ float tile[64][65];
    int bid = blockIdx.x;
    int ct = bid & 3, h = (bid >> 2) & 63, b = bid >> 8;
    int t = threadIdx.x;
    int tr = t >> 4, tc = t & 15;
    const float* src = x + (((size_t)(b * 256 + ct * 64) * 64 + h) * 64);
#pragma unroll
    for (int i = 0; i < 4; ++i) {
        int c = tr + i * 16;
        float4 v = *(const float4*)(src + (size_t)c * 4096 + tc * 4);
        tile[c][tc * 4 + 0] = v.x;
        tile[c][tc * 4 + 1] = v.y;
        tile[c][tc * 4 + 2] = v.z;
        tile[c][tc * 4 + 3] = v.w;
    }
    __syncthreads();
    u16* dst = xp + ((size_t)((b * 64 + h) * 64)) * 256 + ct * 64;
#pragma unroll
    for (int i = 0; i < 4; ++i) {
        int w = tr + i * 16;
        ushort4 o;
        o.x = f2bf(tile[tc * 4 + 0][w]);
        o.y = f2bf(tile[tc * 4 + 1][w]);
        o.z = f2bf(tile[tc * 4 + 2][w]);
        o.w = f2bf(tile[tc * 4 + 3][w]);
        *(ushort4*)(dst + (size_t)w * 256 + tc * 4) = o;
    }
}

// ---------------- weight prep ------------------------------------------------
__global__ __launch_bounds__(256) void prep_w(const float* __restrict__ qw,
                                              const float* __restrict__ qb,
                                              const float* __restrict__ fw,
                                              const float* __restrict__ fb,
                                              float* __restrict__ wq0,
                                              u16* __restrict__ wkv,
                                              float* __restrict__ bkv,
                                              u16* __restrict__ wf,
                                              float* __restrict__ bff) {
    int i = blockIdx.x * 256 + threadIdx.x;
    if (i < 513 * 256) {
        int o = i >> 8, c = i & 255;
        float v = qw[i];
        if (o == 0) wq0[c] = v;
        else        wkv[(size_t)(o - 1) * 256 + c] = f2bf(v);
    }
    if (i < 65536) wf[i] = f2bf(fw[i]);
    if (i < 512)   bkv[i] = qb[i + 1];
    if (i < 256)   bff[i] = fb[i];
}

// ---------------- fused qkv GEMM + softmax + context + gated residual --------
// Block = 128 rows = 2 complete attention lines. 512 threads (8 waves).
// LDS: A panel 128x256 bf16 (64KB, XOR-swizzled) + B tile 128x256 (64KB).
// Key tiles (ot 0,1): MFMA -> ctx accumulate (bias folds: sum(scores)=1).
// Val tiles (ot 2,3): MFMA -> G = x + sigmoid(v)*ctx, x read from LDS A.
template <int AXIS>
__global__ __launch_bounds__(512, 2) void qkv_attn(
    const u16* __restrict__ A, const u16* __restrict__ Bw,
    const float* __restrict__ bkv, const float* __restrict__ wq0,
    u16* __restrict__ G) {
    __shared__ alignas(16) u16 Asm[128 * 256];
    __shared__ alignas(16) u16 Bsm[128 * 256];
    __shared__ float ql[128];
    __shared__ float sc[128];
    __shared__ float ctxs[2][256];
    int t = threadIdx.x, lane = t & 63, wv = t >> 6;
    int beta = blockIdx.x;
    auto prow = [&](int r) -> size_t {
        if (AXIS == 0) return (size_t)beta * 128 + r;
        else           return (size_t)(beta >> 5) * 4096 + (size_t)(r & 63) * 64 +
                              ((beta & 31) * 2) + (r >> 6);
    };
    // ---- stage A panel (8 rounds x 16 rows); swizzle: slot = chunk ^ (row&7)
    {
        int r5 = t >> 5, c5 = t & 31;
#pragma unroll
        for (int i = 0; i < 8; ++i) {
            int row = i * 16 + r5;
            int slot = c5 ^ (row & 7);
            gload16(A + prow(row) * 256 + slot * 8, &Asm[(i * 16 + wv * 2) * 256]);
        }
    }
    __syncthreads();
    // ---- q-dot: 4 threads per row ----
    {
        int row = t >> 2, g = t & 3;
        const float* wp = wq0 + g * 64;
        float a = 0.f;
#pragma unroll
        for (int cc = 0; cc < 8; ++cc) {
            int slot = (g * 8 + cc) ^ (row & 7);
            bf16x8 v = *(const bf16x8*)&Asm[row * 256 + slot * 8];
#pragma unroll
            for (int j = 0; j < 8; ++j) a += bf2f((u16)v[j]) * wp[cc * 8 + j];
        }
        a += __shfl_xor(a, 1);
        a += __shfl_xor(a, 2);
        if (g == 0) ql[row] = a;
    }
    __syncthreads();
    // ---- softmax per line (wave 0 -> line 0, wave 1 -> line 1) ----
    if (t < 128) {
        float qv = ql[t];
        float m = qv;
#pragma unroll
        for (int off = 32; off > 0; off >>= 1) m = fmaxf(m, __shfl_xor(m, off));
        float e = __expf(qv - m);
        float s = e;
#pragma unroll
        for (int off = 32; off > 0; off >>= 1) s += __shfl_xor(s, off);
        sc[t] = e / s;
    }
    // ---- o-tile loop ----
    int wm = (wv & 1) * 64, wn = (wv >> 1) * 32;
    int arow = lane & 15, kgrp = lane >> 4, l7 = lane & 7;
    int line = wv & 1;
    for (int ot = 0; ot < 4; ++ot) {
        __syncthreads();
        {
            int r5 = t >> 5, c5 = t & 31;
#pragma unroll
            for (int i = 0; i < 8; ++i) {
                int row = i * 16 + r5;
                int slot = c5 ^ (row & 7);
                gload16(Bw + (size_t)(ot * 128 + row) * 256 + slot * 8,
                        &Bsm[(i * 16 + wv * 2) * 256]);
            }
        }
        __syncthreads();
        f32x4 zero = {0.f, 0.f, 0.f, 0.f};
        f32x4 acc[4][2];
#pragma unroll
        for (int mi = 0; mi < 4; ++mi) {
            acc[mi][0] = zero;
            acc[mi][1] = zero;
        }
#pragma unroll
        for (int ks = 0; ks < 8; ++ks) {
            int soff = ((ks * 4 + kgrp) ^ l7) * 8;
            bf16x8 af[4], bf[2];
#pragma unroll
            for (int mi = 0; mi < 4; ++mi)
                af[mi] = *(const bf16x8*)&Asm[(wm + mi * 16 + arow) * 256 + soff];
#pragma unroll
            for (int ni = 0; ni < 2; ++ni)
                bf[ni] = *(const bf16x8*)&Bsm[(wn + ni * 16 + arow) * 256 + soff];
#pragma unroll
            for (int mi = 0; mi < 4; ++mi)
#pragma unroll
                for (int ni = 0; ni < 2; ++ni)
                    acc[mi][ni] = __builtin_amdgcn_mfma_f32_16x16x32_bf16(
                        af[mi], bf[ni], acc[mi][ni], 0, 0, 0);
        }
        if (ot < 2) {
            // key: ctx[line][col] = sum_rows sc*key + bias (sum sc = 1)
#pragma unroll
            for (int ni = 0; ni < 2; ++ni) {
                int col = ot * 128 + wn + ni * 16 + arow;
                float part = 0.f;
#pragma unroll
                for (int mi = 0; mi < 4; ++mi) {
                    int rbase = wm + mi * 16 + kgrp * 4;
#pragma unroll
                    for (int r = 0; r < 4; ++r)
                        part += acc[mi][ni][r] * sc[rbase + r];
                }
                part += __shfl_xor(part, 16);
                part += __shfl_xor(part, 32);
                if (lane < 16) ctxs[line][col] = part + bkv[col];
            }
        } else {
            // val: gate + residual + write G
#pragma unroll
            for (int ni = 0; ni < 2; ++ni) {
                int c = (ot - 2) * 128 + wn + ni * 16 + arow;
                float bv = bkv[256 + c];
                float cx = ctxs[line][c];
#pragma unroll
                for (int mi = 0; mi < 4; ++mi) {
#pragma unroll
                    for (int r = 0; r < 4; ++r) {
                        int row = wm + mi * 16 + kgrp * 4 + r;
                        float v = acc[mi][ni][r] + bv;
                        int slot = (c >> 3) ^ (row & 7);
                        float xv = bf2f(Asm[row * 256 + slot * 8 + (c & 7)]);
                        G[prow(row) * 256 + c] = f2bf(xv + sigm(v) * cx);
                    }
                }
            }
        }
    }
}

// ---------------- fusion GEMM: MODE 1 = bf16 out, MODE 2 = fp32 transposed out
template <int MODE>
__global__ __launch_bounds__(256, 2) void gemm_k(
    const u16* __restrict__ A, const u16* __restrict__ Bw,
    const float* __restrict__ bias,
    u16* __restrict__ bOut, float* __restrict__ fOut) {
    int h = blockIdx.x;
    int xcd = h & 7, slot = h >> 3;
    int otile = slot & 1, ptile = xcd * 64 + (slot >> 1);
    __shared__ alignas(16) u16 Asm[128 * 64];
    __shared__ alignas(16) u16 Bsm[128 * 64];
    int p0 = ptile * 128, o0 = otile * 128;
    int t = threadIdx.x, lane = t & 63, wv = t >> 6;
    int wm = (wv >> 1) * 64, wn = (wv & 1) * 64;
    int l7 = lane & 7;
    int srcoff = (lane >> 3) * 256 + (((lane & 7) ^ (lane >> 3)) * 8);
    int arow = lane & 15, kgrp = lane >> 4;
    f32x4 zero = {0.f, 0.f, 0.f, 0.f};
    f32x4 acc[4][4];
#pragma unroll
    for (int i = 0; i < 4; ++i)
#pragma unroll
        for (int jj = 0; jj < 4; ++jj) acc[i][jj] = zero;

    for (int k0 = 0; k0 < 256; k0 += 64) {
        __syncthreads();
#pragma unroll
        for (int it = 0; it < 4; ++it) {
            int r0 = it * 32 + wv * 8;
            gload16(A + (size_t)(p0 + r0) * 256 + k0 + srcoff, &Asm[r0 * 64]);
            gload16(Bw + (size_t)(o0 + r0) * 256 + k0 + srcoff, &Bsm[r0 * 64]);
        }
        __syncthreads();
#pragma unroll
        for (int kk = 0; kk < 64; kk += 32) {
            int soff = (((kk >> 3) + kgrp) ^ l7) << 3;
            bf16x8 af[4], bfv[4];
#pragma unroll
            for (int mi = 0; mi < 4; ++mi)
                af[mi] = *(const bf16x8*)&Asm[(wm + mi * 16 + arow) * 64 + soff];
#pragma unroll
            for (int ni = 0; ni < 4; ++ni)
                bfv[ni] = *(const bf16x8*)&Bsm[(wn + ni * 16 + arow) * 64 + soff];
#pragma unroll
            for (int mi = 0; mi < 4; ++mi)
#pragma unroll
                for (int ni = 0; ni < 4; ++ni)
                    acc[mi][ni] = __builtin_amdgcn_mfma_f32_16x16x32_bf16(
                        af[mi], bfv[ni], acc[mi][ni], 0, 0, 0);
        }
    }
#pragma unroll
    for (int mi = 0; mi < 4; ++mi) {
#pragma unroll
        for (int ni = 0; ni < 4; ++ni) {
            int col = o0 + wn + ni * 16 + arow;
            float bv = bias[col];
#pragma unroll
            for (int r = 0; r < 4; ++r) {
                int row = p0 + wm + mi * 16 + ((lane >> 4) << 2) + r;
                float v = acc[mi][ni][r] + bv;
                if (MODE == 1) {
                    bOut[(size_t)row * 256 + col] = f2bf(v);
                } else {
                    fOut[((size_t)((row >> 12) * 256 + col)) * 4096 + (row & 4095)] = v;
                }
            }
        }
    }
}

// ---------------- host ----------------
extern "C" void kernel_launch(void* const* d_in, const int* in_sizes, int n_in,
                              void* d_out, int out_size, void* d_ws, size_t ws_size,
                              hipStream_t stream) {
    const float* x   = (const float*)d_in[0];
    const float* qWw = (const float*)d_in[1];
    const float* qWb = (const float*)d_in[2];
    const float* qHw = (const float*)d_in[3];
    const float* qHb = (const float*)d_in[4];
    const float* fWw = (const float*)d_in[5];
    const float* fWb = (const float*)d_in[6];
    const float* fHw = (const float*)d_in[7];
    const float* fHb = (const float*)d_in[8];
    float* out = (float*)d_out;

    char* ws = (char*)d_ws;
    size_t off = 0;
    auto carve = [&](size_t bytes) -> void* {
        off = (off + 255) & ~(size_t)255;
        void* p = ws + off;
        off += bytes;
        return p;
    };
    const size_t P = 65536;
    u16*   xp  = (u16*)carve(P * 256 * 2);   // x'
    u16*   kb  = (u16*)carve(P * 256 * 2);   // G (both stages)
    u16*   vb  = (u16*)carve(P * 256 * 2);   // x_w'
    float* wq01 = (float*)carve(256 * 4);
    u16*   wkv1 = (u16*)carve(512 * 256 * 2);
    float* bkv1 = (float*)carve(512 * 4);
    u16*   wf1  = (u16*)carve(65536 * 2);
    float* bf1  = (float*)carve(256 * 4);
    float* wq02 = (float*)carve(256 * 4);
    u16*   wkv2 = (u16*)carve(512 * 256 * 2);
    float* bkv2 = (float*)carve(512 * 4);
    u16*   wf2  = (u16*)carve(65536 * 2);
    float* bf2  = (float*)carve(256 * 4);

    prep_w<<<513, 256, 0, stream>>>(qWw, qWb, fWw, fWb, wq01, wkv1, bkv1, wf1, bf1);
    prep_w<<<513, 256, 0, stream>>>(qHw, qHb, fHw, fHb, wq02, wkv2, bkv2, wf2, bf2);
    transpose_in<<<4096, 256, 0, stream>>>(x, xp);

    // ---- stage 1 (axis = W) ----
    qkv_attn<0><<<512, 512, 0, stream>>>(xp, wkv1, bkv1, wq01, kb);
    gemm_k<1><<<1024, 256, 0, stream>>>(kb, wf1, bf1, vb, nullptr);   // x_w' -> vb
    // ---- stage 2 (axis = H) ----
    qkv_attn<1><<<512, 512, 0, stream>>>(vb, wkv2, bkv2, wq02, kb);
    gemm_k<2><<<1024, 256, 0, stream>>>(kb, wf2, bf2, nullptr, out);
    (void)in_sizes; (void)n_in; (void)out_size; (void)ws_size;
}

// Round 5
// 159.135 us; speedup vs baseline: 1.9163x; 1.0092x over previous
//
#include <hip/hip_runtime.h>

typedef unsigned short u16;
typedef unsigned int u32;
typedef __attribute__((ext_vector_type(8))) short bf16x8;
typedef __attribute__((ext_vector_type(4))) float f32x4;

__device__ __forceinline__ u16 f2bf(float f) {
    u32 u = __builtin_bit_cast(u32, f);
    u += 0x7FFFu + ((u >> 16) & 1u);
    return (u16)(u >> 16);
}
__device__ __forceinline__ float bf2f(u16 s) {
    u32 u = ((u32)s) << 16;
    return __builtin_bit_cast(float, u);
}
__device__ __forceinline__ float sigm(float x) {
    return 1.0f / (1.0f + __expf(-x));
}
__device__ __forceinline__ void gload16(const u16* g, u16* l) {
    __builtin_amdgcn_global_load_lds(
        (const __attribute__((address_space(1))) void*)g,
        (__attribute__((address_space(3))) void*)l, 16, 0, 0);
}

// ---------------- P1: x (B,C,H,W) fp32 -> x' [p][c] bf16, p=(b*64+h)*64+w ----
__global__ __launch_bounds__(256) void transpose_in(const float* __restrict__ x,
                                                    u16* __restrict__ xp) {
    __shared__ float tile[64][65];
    int bid = blockIdx.x;
    int ct = bid & 3, h = (bid >> 2) & 63, b = bid >> 8;
    int t = threadIdx.x;
    int tr = t >> 4, tc = t & 15;
    const float* src = x + (((size_t)(b * 256 + ct * 64) * 64 + h) * 64);
#pragma unroll
    for (int i = 0; i < 4; ++i) {
        int c = tr + i * 16;
        float4 v = *(const float4*)(src + (size_t)c * 4096 + tc * 4);
        tile[c][tc * 4 + 0] = v.x;
        tile[c][tc * 4 + 1] = v.y;
        tile[c][tc * 4 + 2] = v.z;
        tile[c][tc * 4 + 3] = v.w;
    }
    __syncthreads();
    u16* dst = xp + ((size_t)((b * 64 + h) * 64)) * 256 + ct * 64;
#pragma unroll
    for (int i = 0; i < 4; ++i) {
        int w = tr + i * 16;
        ushort4 o;
        o.x = f2bf(tile[tc * 4 + 0][w]);
        o.y = f2bf(tile[tc * 4 + 1][w]);
        o.z = f2bf(tile[tc * 4 + 2][w]);
        o.w = f2bf(tile[tc * 4 + 3][w]);
        *(ushort4*)(dst + (size_t)w * 256 + tc * 4) = o;
    }
}

// ---------------- weight prep ------------------------------------------------
__global__ __launch_bounds__(256) void prep_w(const float* __restrict__ qw,
                                              const float* __restrict__ qb,
                                              const float* __restrict__ fw,
                                              const float* __restrict__ fb,
                                              float* __restrict__ wq0,
                                              u16* __restrict__ wkv,
                                              float* __restrict__ bkv,
                                              u16* __restrict__ wf,
                                              float* __restrict__ bff) {
    int i = blockIdx.x * 256 + threadIdx.x;
    if (i < 513 * 256) {
        int o = i >> 8, c = i & 255;
        float v = qw[i];
        if (o == 0) wq0[c] = v;
        else        wkv[(size_t)(o - 1) * 256 + c] = f2bf(v);
    }
    if (i < 65536) wf[i] = f2bf(fw[i]);
    if (i < 512)   bkv[i] = qb[i + 1];
    if (i < 256)   bff[i] = fb[i];
}

// ---------------- fused qkv GEMM + softmax + context + gated residual v2 -----
// Block = 128 rows = 2 lines (line = local row >> 6 for both axes).
// 512 threads (8 waves): wave = rowhalf(=line, wv>>2) x 32-ch block (wv&3).
// LDS: A panel only (64KB, XOR-swizzled) -> 2 blocks/CU. W streamed from L2
// straight into VGPR fragments (no B staging, no per-ot barriers).
// MFMA operand-swapped: D[ch][row]; lane holds 4 consecutive channels.
template <int AXIS>
__global__ __launch_bounds__(512, 4) void qkv_attn(
    const u16* __restrict__ A, const u16* __restrict__ Bw,
    const float* __restrict__ bkv, const float* __restrict__ wq0,
    u16* __restrict__ G) {
    __shared__ alignas(16) u16 Asm[128 * 256];
    __shared__ float ql[128];
    __shared__ float sc[128];
    __shared__ alignas(16) float ctxs[2][256];
    int t = threadIdx.x, lane = t & 63, wv = t >> 6;
    int beta = blockIdx.x;
    auto prow = [&](int r) -> size_t {
        if (AXIS == 0) return (size_t)beta * 128 + r;
        else           return (size_t)(beta >> 5) * 4096 + (size_t)(r & 63) * 64 +
                              ((beta & 31) * 2) + (r >> 6);
    };
    // ---- stage A panel; swizzle: stored chunk = src chunk ^ (row&7) ----
    {
#pragma unroll
        for (int i = 0; i < 8; ++i) {
            int row = i * 16 + wv * 2 + (lane >> 5);
            int slot = (lane & 31) ^ (row & 7);
            gload16(A + prow(row) * 256 + slot * 8, &Asm[(i * 16 + wv * 2) * 256]);
        }
    }
    __syncthreads();
    // ---- q-dot: 4 threads per row ----
    {
        int row = t >> 2, g = t & 3;
        const float* wp = wq0 + g * 64;
        float a = 0.f;
#pragma unroll
        for (int cc = 0; cc < 8; ++cc) {
            int slot = (g * 8 + cc) ^ (row & 7);
            bf16x8 v = *(const bf16x8*)&Asm[row * 256 + slot * 8];
#pragma unroll
            for (int j = 0; j < 8; ++j) a += bf2f((u16)v[j]) * wp[cc * 8 + j];
        }
        a += __shfl_xor(a, 1);
        a += __shfl_xor(a, 2);
        if (g == 0) ql[row] = a;
    }
    __syncthreads();
    // ---- softmax per line (waves 0,1) ----
    if (t < 128) {
        float qv = ql[t];
        float m = qv;
#pragma unroll
        for (int off = 32; off > 0; off >>= 1) m = fmaxf(m, __shfl_xor(m, off));
        float e = __expf(qv - m);
        float s = e;
#pragma unroll
        for (int off = 32; off > 0; off >>= 1) s += __shfl_xor(s, off);
        sc[t] = e / s;
    }
    __syncthreads();
    // ---- o-tile loop (no staging barriers) ----
    int rowhalf = wv >> 2, chq = wv & 3;
    int arow = lane & 15, kgrp = lane >> 4;
    float sv[4];
#pragma unroll
    for (int ni = 0; ni < 4; ++ni) sv[ni] = sc[rowhalf * 64 + ni * 16 + arow];
    for (int ot = 0; ot < 4; ++ot) {
        f32x4 zero = {0.f, 0.f, 0.f, 0.f};
        f32x4 acc[2][4];
#pragma unroll
        for (int mi = 0; mi < 2; ++mi)
#pragma unroll
            for (int ni = 0; ni < 4; ++ni) acc[mi][ni] = zero;
#pragma unroll
        for (int ks = 0; ks < 8; ++ks) {
            bf16x8 aw[2], bx[4];
#pragma unroll
            for (int mi = 0; mi < 2; ++mi)
                aw[mi] = *(const bf16x8*)(Bw +
                    (size_t)(ot * 128 + chq * 32 + mi * 16 + arow) * 256 +
                    ks * 32 + kgrp * 8);
#pragma unroll
            for (int ni = 0; ni < 4; ++ni) {
                int p = rowhalf * 64 + ni * 16 + arow;
                int slot = (ks * 4 + kgrp) ^ (p & 7);
                bx[ni] = *(const bf16x8*)&Asm[p * 256 + slot * 8];
            }
#pragma unroll
            for (int mi = 0; mi < 2; ++mi)
#pragma unroll
                for (int ni = 0; ni < 4; ++ni)
                    acc[mi][ni] = __builtin_amdgcn_mfma_f32_16x16x32_bf16(
                        aw[mi], bx[ni], acc[mi][ni], 0, 0, 0);
        }
        if (ot < 2) {
            // key: ctx[line][c..c+3] = sum_p sc[p]*key[p][c] + bkv[c]
#pragma unroll
            for (int mi = 0; mi < 2; ++mi) {
                int c = ot * 128 + chq * 32 + mi * 16 + kgrp * 4;
                f32x4 red;
#pragma unroll
                for (int r = 0; r < 4; ++r) {
                    float s = 0.f;
#pragma unroll
                    for (int ni = 0; ni < 4; ++ni) s += acc[mi][ni][r] * sv[ni];
                    s += __shfl_xor(s, 1);
                    s += __shfl_xor(s, 2);
                    s += __shfl_xor(s, 4);
                    s += __shfl_xor(s, 8);
                    red[r] = s;
                }
                if (arow == 0) {
                    f32x4 bv = *(const f32x4*)&bkv[c];
                    red[0] += bv[0]; red[1] += bv[1];
                    red[2] += bv[2]; red[3] += bv[3];
                    *(f32x4*)&ctxs[rowhalf][c] = red;
                }
            }
        } else {
            // val: G[p][c..c+3] = x + sigmoid(v+bias)*ctx
#pragma unroll
            for (int mi = 0; mi < 2; ++mi) {
                int cv = (ot - 2) * 128 + chq * 32 + mi * 16 + kgrp * 4;
                f32x4 bv = *(const f32x4*)&bkv[256 + cv];
                f32x4 cxv = *(const f32x4*)&ctxs[rowhalf][cv];
#pragma unroll
                for (int ni = 0; ni < 4; ++ni) {
                    int p = rowhalf * 64 + ni * 16 + arow;
                    int slot = (cv >> 3) ^ (p & 7);
                    ushort4 xv = *(const ushort4*)&Asm[p * 256 + slot * 8 + (cv & 7)];
                    ushort4 o;
                    o.x = f2bf(bf2f(xv.x) + sigm(acc[mi][ni][0] + bv[0]) * cxv[0]);
                    o.y = f2bf(bf2f(xv.y) + sigm(acc[mi][ni][1] + bv[1]) * cxv[1]);
                    o.z = f2bf(bf2f(xv.z) + sigm(acc[mi][ni][2] + bv[2]) * cxv[2]);
                    o.w = f2bf(bf2f(xv.w) + sigm(acc[mi][ni][3] + bv[3]) * cxv[3]);
                    *(ushort4*)(G + prow(p) * 256 + cv) = o;
                }
            }
        }
        if (ot == 1) __syncthreads();  // ctxs ready before val tiles
    }
}

// ---------------- fusion GEMM: MODE 1 = bf16 out, MODE 2 = fp32 transposed out
template <int MODE>
__global__ __launch_bounds__(256, 2) void gemm_k(
    const u16* __restrict__ A, const u16* __restrict__ Bw,
    const float* __restrict__ bias,
    u16* __restrict__ bOut, float* __restrict__ fOut) {
    int h = blockIdx.x;
    int xcd = h & 7, slot = h >> 3;
    int otile = slot & 1, ptile = xcd * 64 + (slot >> 1);
    __shared__ alignas(16) u16 Asm[128 * 64];
    __shared__ alignas(16) u16 Bsm[128 * 64];
    int p0 = ptile * 128, o0 = otile * 128;
    int t = threadIdx.x, lane = t & 63, wv = t >> 6;
    int wm = (wv >> 1) * 64, wn = (wv & 1) * 64;
    int l7 = lane & 7;
    int srcoff = (lane >> 3) * 256 + (((lane & 7) ^ (lane >> 3)) * 8);
    int arow = lane & 15, kgrp = lane >> 4;
    f32x4 zero = {0.f, 0.f, 0.f, 0.f};
    f32x4 acc[4][4];
#pragma unroll
    for (int i = 0; i < 4; ++i)
#pragma unroll
        for (int jj = 0; jj < 4; ++jj) acc[i][jj] = zero;

    for (int k0 = 0; k0 < 256; k0 += 64) {
        __syncthreads();
#pragma unroll
        for (int it = 0; it < 4; ++it) {
            int r0 = it * 32 + wv * 8;
            gload16(A + (size_t)(p0 + r0) * 256 + k0 + srcoff, &Asm[r0 * 64]);
            gload16(Bw + (size_t)(o0 + r0) * 256 + k0 + srcoff, &Bsm[r0 * 64]);
        }
        __syncthreads();
#pragma unroll
        for (int kk = 0; kk < 64; kk += 32) {
            int soff = (((kk >> 3) + kgrp) ^ l7) << 3;
            bf16x8 af[4], bfv[4];
#pragma unroll
            for (int mi = 0; mi < 4; ++mi)
                af[mi] = *(const bf16x8*)&Asm[(wm + mi * 16 + arow) * 64 + soff];
#pragma unroll
            for (int ni = 0; ni < 4; ++ni)
                bfv[ni] = *(const bf16x8*)&Bsm[(wn + ni * 16 + arow) * 64 + soff];
#pragma unroll
            for (int mi = 0; mi < 4; ++mi)
#pragma unroll
                for (int ni = 0; ni < 4; ++ni)
                    acc[mi][ni] = __builtin_amdgcn_mfma_f32_16x16x32_bf16(
                        af[mi], bfv[ni], acc[mi][ni], 0, 0, 0);
        }
    }
#pragma unroll
    for (int mi = 0; mi < 4; ++mi) {
#pragma unroll
        for (int ni = 0; ni < 4; ++ni) {
            int col = o0 + wn + ni * 16 + arow;
            float bv = bias[col];
#pragma unroll
            for (int r = 0; r < 4; ++r) {
                int row = p0 + wm + mi * 16 + ((lane >> 4) << 2) + r;
                float v = acc[mi][ni][r] + bv;
                if (MODE == 1) {
                    bOut[(size_t)row * 256 + col] = f2bf(v);
                } else {
                    fOut[((size_t)((row >> 12) * 256 + col)) * 4096 + (row & 4095)] = v;
                }
            }
        }
    }
}

// ---------------- host ----------------
extern "C" void kernel_launch(void* const* d_in, const int* in_sizes, int n_in,
                              void* d_out, int out_size, void* d_ws, size_t ws_size,
                              hipStream_t stream) {
    const float* x   = (const float*)d_in[0];
    const float* qWw = (const float*)d_in[1];
    const float* qWb = (const float*)d_in[2];
    const float* qHw = (const float*)d_in[3];
    const float* qHb = (const float*)d_in[4];
    const float* fWw = (const float*)d_in[5];
    const float* fWb = (const float*)d_in[6];
    const float* fHw = (const float*)d_in[7];
    const float* fHb = (const float*)d_in[8];
    float* out = (float*)d_out;

    char* ws = (char*)d_ws;
    size_t off = 0;
    auto carve = [&](size_t bytes) -> void* {
        off = (off + 255) & ~(size_t)255;
        void* p = ws + off;
        off += bytes;
        return p;
    };
    const size_t P = 65536;
    u16*   xp  = (u16*)carve(P * 256 * 2);   // x'
    u16*   kb  = (u16*)carve(P * 256 * 2);   // G (both stages)
    u16*   vb  = (u16*)carve(P * 256 * 2);   // x_w'
    float* wq01 = (float*)carve(256 * 4);
    u16*   wkv1 = (u16*)carve(512 * 256 * 2);
    float* bkv1 = (float*)carve(512 * 4);
    u16*   wf1  = (u16*)carve(65536 * 2);
    float* bf1  = (float*)carve(256 * 4);
    float* wq02 = (float*)carve(256 * 4);
    u16*   wkv2 = (u16*)carve(512 * 256 * 2);
    float* bkv2 = (float*)carve(512 * 4);
    u16*   wf2  = (u16*)carve(65536 * 2);
    float* bf2  = (float*)carve(256 * 4);

    prep_w<<<513, 256, 0, stream>>>(qWw, qWb, fWw, fWb, wq01, wkv1, bkv1, wf1, bf1);
    prep_w<<<513, 256, 0, stream>>>(qHw, qHb, fHw, fHb, wq02, wkv2, bkv2, wf2, bf2);
    transpose_in<<<4096, 256, 0, stream>>>(x, xp);

    // ---- stage 1 (axis = W) ----
    qkv_attn<0><<<512, 512, 0, stream>>>(xp, wkv1, bkv1, wq01, kb);
    gemm_k<1><<<1024, 256, 0, stream>>>(kb, wf1, bf1, vb, nullptr);   // x_w' -> vb
    // ---- stage 2 (axis = H) ----
    qkv_attn<1><<<512, 512, 0, stream>>>(vb, wkv2, bkv2, wq02, kb);
    gemm_k<2><<<1024, 256, 0, stream>>>(kb, wf2, bf2, nullptr, out);
    (void)in_sizes; (void)n_in; (void)out_size; (void)ws_size;
}